// Round 1
// baseline (612.230 us; speedup 1.0000x reference)
//
#include <hip/hip_runtime.h>
#include <stdint.h>

#define D_MODEL 2048
#define SEQ     2048
#define BATCH   2
#define NHEAD   16
#define HD      128
#define MROWS   (BATCH*SEQ)   // 4096

typedef short short8 __attribute__((ext_vector_type(8)));
typedef float f32x4  __attribute__((ext_vector_type(4)));

__device__ __forceinline__ unsigned short f2b(float f) {
  unsigned int u = __float_as_uint(f);
  u += 0x7fffu + ((u >> 16) & 1u);          // RNE
  return (unsigned short)(u >> 16);
}
__device__ __forceinline__ float b2f(unsigned short s) {
  return __uint_as_float(((unsigned int)s) << 16);
}
__device__ __forceinline__ void gll16(const void* g, void* l) {
  __builtin_amdgcn_global_load_lds((const __attribute__((address_space(1))) void*)g,
                                   (__attribute__((address_space(3))) void*)l, 16, 0, 0);
}

// ---------------- cast fp32 -> bf16 (x | Wq | Wk | Wv | Wo contiguous) ----------------
__global__ __launch_bounds__(256) void cast_all(
    const float* __restrict__ x,  const float* __restrict__ Wq,
    const float* __restrict__ Wk, const float* __restrict__ Wv,
    const float* __restrict__ Wo, unsigned short* __restrict__ dst)
{
  size_t e = ((size_t)blockIdx.x * 256 + threadIdx.x) * 4;
  const size_t XN = (size_t)MROWS * D_MODEL;   // 2^23
  const size_t WN = (size_t)D_MODEL * D_MODEL; // 2^22
  const float* src; size_t off;
  if (e < XN) { src = x; off = e; }
  else {
    size_t e2 = e - XN;
    int w = (int)(e2 >> 22);
    off = e2 & (WN - 1);
    src = (w == 0) ? Wq : (w == 1) ? Wk : (w == 2) ? Wv : Wo;
  }
  float4 v = *(const float4*)(src + off);
  ushort4 o;
  o.x = f2b(v.x); o.y = f2b(v.y); o.z = f2b(v.z); o.w = f2b(v.w);
  *(ushort4*)(dst + e) = o;
}

// ---------------- m97-style 128x128 bf16 GEMM core: C = A @ B^T ----------------
// A: [M,K] bf16 row-major (K contig), Bw: [N,K] bf16 row-major (K contig)
__device__ __forceinline__ void gemm_core(
    const unsigned short* __restrict__ A, const unsigned short* __restrict__ Bw,
    unsigned short* As, unsigned short* Bs, int m0, int n0, int tid,
    f32x4 (&acc)[4][4])
{
  const int K = D_MODEL;
  const int wave = tid >> 6, lane = tid & 63, l15 = lane & 15, quad = lane >> 4;
  const int wr = wave >> 1, wc = wave & 1;

  for (int kt = 0; kt < K; kt += 32) {
    #pragma unroll
    for (int c = 0; c < 2; ++c) {
      int chunk = c * 256 + tid;
      const unsigned short* ga = A  + (size_t)(m0 + (chunk >> 2)) * K + kt + (chunk & 3) * 8;
      const unsigned short* gb = Bw + (size_t)(n0 + (chunk >> 2)) * K + kt + (chunk & 3) * 8;
      gll16(ga, As + (size_t)(c * 256 + wave * 64) * 8);  // dest = wave-uniform base + lane*16
      gll16(gb, Bs + (size_t)(c * 256 + wave * 64) * 8);
    }
    __syncthreads();
    short8 af[4], bfr[4];
    #pragma unroll
    for (int mi = 0; mi < 4; ++mi)
      af[mi] = *(const short8*)(As + (wr * 64 + mi * 16 + l15) * 32 + quad * 8);
    #pragma unroll
    for (int ni = 0; ni < 4; ++ni)
      bfr[ni] = *(const short8*)(Bs + (wc * 64 + ni * 16 + l15) * 32 + quad * 8);
    #pragma unroll
    for (int mi = 0; mi < 4; ++mi)
      #pragma unroll
      for (int ni = 0; ni < 4; ++ni)
        acc[mi][ni] = __builtin_amdgcn_mfma_f32_16x16x32_bf16(af[mi], bfr[ni], acc[mi][ni], 0, 0, 0);
    __syncthreads();
  }
}

// QKV: z picks weight; Q,K -> [b,h,s,d] bf16; V -> [b,h,d,s] bf16 (transposed in epilogue)
__global__ __launch_bounds__(256) void gemm_qkv(
    const unsigned short* __restrict__ Axb,
    const unsigned short* __restrict__ Wq, const unsigned short* __restrict__ Wk,
    const unsigned short* __restrict__ Wv,
    unsigned short* __restrict__ Qh, unsigned short* __restrict__ Kh,
    unsigned short* __restrict__ Vt)
{
  __shared__ unsigned short As[128 * 32], Bs[128 * 32];
  const int z = blockIdx.z;
  const unsigned short* Bw = (z == 0) ? Wq : (z == 1) ? Wk : Wv;
  const int m0 = blockIdx.y * 128, n0 = blockIdx.x * 128;
  f32x4 acc[4][4];
  #pragma unroll
  for (int i = 0; i < 4; ++i)
    #pragma unroll
    for (int j = 0; j < 4; ++j) acc[i][j] = (f32x4){0.f, 0.f, 0.f, 0.f};
  gemm_core(Axb, Bw, As, Bs, m0, n0, threadIdx.x, acc);

  const int tid = threadIdx.x, wave = tid >> 6, lane = tid & 63;
  const int l15 = lane & 15, quad = lane >> 4, wr = wave >> 1, wc = wave & 1;
  if (z < 2) {
    unsigned short* dst = z ? Kh : Qh;
    #pragma unroll
    for (int mi = 0; mi < 4; ++mi)
      #pragma unroll
      for (int ni = 0; ni < 4; ++ni) {
        int row0 = m0 + wr * 64 + mi * 16 + quad * 4;
        int col  = n0 + wc * 64 + ni * 16 + l15;
        int h = col >> 7, d = col & (HD - 1);
        #pragma unroll
        for (int r = 0; r < 4; ++r) {
          int m = row0 + r; int bb = m >> 11; int s = m & (SEQ - 1);
          dst[((size_t)(bb * NHEAD + h) * SEQ + s) * HD + d] = f2b(acc[mi][ni][r]);
        }
      }
  } else {
    #pragma unroll
    for (int mi = 0; mi < 4; ++mi)
      #pragma unroll
      for (int ni = 0; ni < 4; ++ni) {
        int row0 = m0 + wr * 64 + mi * 16 + quad * 4;   // 4-aligned, no batch straddle
        int col  = n0 + wc * 64 + ni * 16 + l15;
        int h = col >> 7, d = col & (HD - 1);
        int bb = row0 >> 11; int s = row0 & (SEQ - 1);
        ushort4 pk;
        pk.x = f2b(acc[mi][ni][0]); pk.y = f2b(acc[mi][ni][1]);
        pk.z = f2b(acc[mi][ni][2]); pk.w = f2b(acc[mi][ni][3]);
        *(ushort4*)(Vt + ((size_t)(bb * NHEAD + h) * HD + d) * SEQ + s) = pk;
      }
  }
}

__global__ __launch_bounds__(256) void gemm_out(
    const unsigned short* __restrict__ A, const unsigned short* __restrict__ Wo,
    float* __restrict__ C)
{
  __shared__ unsigned short As[128 * 32], Bs[128 * 32];
  const int m0 = blockIdx.y * 128, n0 = blockIdx.x * 128;
  f32x4 acc[4][4];
  #pragma unroll
  for (int i = 0; i < 4; ++i)
    #pragma unroll
    for (int j = 0; j < 4; ++j) acc[i][j] = (f32x4){0.f, 0.f, 0.f, 0.f};
  gemm_core(A, Wo, As, Bs, m0, n0, threadIdx.x, acc);

  const int tid = threadIdx.x, wave = tid >> 6, lane = tid & 63;
  const int l15 = lane & 15, quad = lane >> 4, wr = wave >> 1, wc = wave & 1;
  #pragma unroll
  for (int mi = 0; mi < 4; ++mi)
    #pragma unroll
    for (int ni = 0; ni < 4; ++ni) {
      int row0 = m0 + wr * 64 + mi * 16 + quad * 4;
      int col  = n0 + wc * 64 + ni * 16 + l15;
      #pragma unroll
      for (int r = 0; r < 4; ++r)
        C[(size_t)(row0 + r) * D_MODEL + col] = acc[mi][ni][r];
    }
}

// ---------------- RoPE in place on [b,h,s,d] bf16 (y: 0=Q, 1=K) ----------------
__global__ __launch_bounds__(256) void rope_k(unsigned short* __restrict__ Qh,
                                              unsigned short* __restrict__ Kh)
{
  unsigned short* P = blockIdx.y ? Kh : Qh;
  int rid = blockIdx.x * 4 + (threadIdx.x >> 6);   // 0..65535 rows of 128
  int i = threadIdx.x & 63;                        // pair index
  int s = rid & (SEQ - 1);
  size_t base = (size_t)rid * HD + 2 * i;
  float inv = exp2f(-(float)i * (13.287712379549449f / 64.0f)); // 10000^(-i/64)
  float ang = (float)s * inv;
  float sn, cs; sincosf(ang, &sn, &cs);
  unsigned int pk = *(const unsigned int*)(P + base);
  float x1 = b2f((unsigned short)(pk & 0xffffu));
  float x2 = b2f((unsigned short)(pk >> 16));
  unsigned short o0 = f2b(x1 * cs - x2 * sn);
  unsigned short o1 = f2b(x1 * sn + x2 * cs);
  *(unsigned int*)(P + base) = (unsigned int)o0 | ((unsigned int)o1 << 16);
}

// ---------------- flash attention: 128 q-rows/block, 32/wave, causal ----------------
__global__ __launch_bounds__(256) void attn_k(
    const unsigned short* __restrict__ Qh, const unsigned short* __restrict__ Kh,
    const unsigned short* __restrict__ Vt, unsigned short* __restrict__ Aout)
{
  __shared__ unsigned short sP[4][32 * 40];   // per-wave P buffer, stride 40 (80B, 16B-aligned rows)
  const int tid = threadIdx.x;
  const int wave = tid >> 6, lane = tid & 63, l15 = lane & 15, quad = lane >> 4;
  const int bh = blockIdx.y;
  const int b = bh >> 4, h = bh & 15;
  const int q0 = blockIdx.x * 128 + wave * 32;
  const unsigned short* Qb = Qh + (size_t)bh * SEQ * HD;
  const unsigned short* Kb = Kh + (size_t)bh * SEQ * HD;
  const unsigned short* Vb = Vt + (size_t)bh * HD * SEQ;
  unsigned short* pbuf = &sP[wave][0];
  const float scl = 0.08838834764831845f * 1.4426950408889634f; // 1/sqrt(128) * log2(e)

  short8 qf[2][4];
  #pragma unroll
  for (int mi = 0; mi < 2; ++mi)
    #pragma unroll
    for (int c = 0; c < 4; ++c)
      qf[mi][c] = *(const short8*)(Qb + (size_t)(q0 + mi * 16 + l15) * HD + c * 32 + quad * 8);

  f32x4 o[2][8];
  #pragma unroll
  for (int mi = 0; mi < 2; ++mi)
    #pragma unroll
    for (int nj = 0; nj < 8; ++nj) o[mi][nj] = (f32x4){0.f, 0.f, 0.f, 0.f};
  float mst[2][4], lst[2][4];
  #pragma unroll
  for (int mi = 0; mi < 2; ++mi)
    #pragma unroll
    for (int r = 0; r < 4; ++r) { mst[mi][r] = -1e30f; lst[mi][r] = 0.f; }

  const int kend = q0 + 31;
  for (int k0 = 0; k0 <= kend; k0 += 32) {
    f32x4 st[2][2];
    #pragma unroll
    for (int mi = 0; mi < 2; ++mi)
      #pragma unroll
      for (int ni = 0; ni < 2; ++ni) st[mi][ni] = (f32x4){0.f, 0.f, 0.f, 0.f};
    #pragma unroll
    for (int ni = 0; ni < 2; ++ni) {
      short8 kf[4];
      #pragma unroll
      for (int c = 0; c < 4; ++c)
        kf[c] = *(const short8*)(Kb + (size_t)(k0 + ni * 16 + l15) * HD + c * 32 + quad * 8);
      #pragma unroll
      for (int mi = 0; mi < 2; ++mi)
        #pragma unroll
        for (int c = 0; c < 4; ++c)
          st[mi][ni] = __builtin_amdgcn_mfma_f32_16x16x32_bf16(qf[mi][c], kf[c], st[mi][ni], 0, 0, 0);
    }

    float p[2][2][4];
    #pragma unroll
    for (int mi = 0; mi < 2; ++mi) {
      bool needmask = (k0 + 31) > (q0 + mi * 16);
      float sm[2][4];
      #pragma unroll
      for (int ni = 0; ni < 2; ++ni)
        #pragma unroll
        for (int r = 0; r < 4; ++r) {
          float s = st[mi][ni][r] * scl;
          if (needmask) {
            int row = q0 + mi * 16 + quad * 4 + r;
            int col = k0 + ni * 16 + l15;
            if (col > row) s = -1e30f;
          }
          sm[ni][r] = s;
        }
      float tm[4];
      #pragma unroll
      for (int r = 0; r < 4; ++r) tm[r] = fmaxf(sm[0][r], sm[1][r]);
      #pragma unroll
      for (int off = 1; off < 16; off <<= 1)
        #pragma unroll
        for (int r = 0; r < 4; ++r) tm[r] = fmaxf(tm[r], __shfl_xor(tm[r], off, 64));
      float al[4];
      #pragma unroll
      for (int r = 0; r < 4; ++r) {
        float mn = fmaxf(mst[mi][r], tm[r]);
        al[r] = exp2f(mst[mi][r] - mn);
        mst[mi][r] = mn;
      }
      float rs[4];
      #pragma unroll
      for (int ni = 0; ni < 2; ++ni)
        #pragma unroll
        for (int r = 0; r < 4; ++r) p[mi][ni][r] = exp2f(sm[ni][r] - mst[mi][r]);
      #pragma unroll
      for (int r = 0; r < 4; ++r) rs[r] = p[mi][0][r] + p[mi][1][r];
      #pragma unroll
      for (int off = 1; off < 16; off <<= 1)
        #pragma unroll
        for (int r = 0; r < 4; ++r) rs[r] += __shfl_xor(rs[r], off, 64);
      f32x4 av;
      #pragma unroll
      for (int r = 0; r < 4; ++r) {
        lst[mi][r] = lst[mi][r] * al[r] + rs[r];
        av[r] = al[r];
      }
      #pragma unroll
      for (int nj = 0; nj < 8; ++nj) o[mi][nj] *= av;
    }

    // P (C/D layout) -> LDS -> A-operand layout
    #pragma unroll
    for (int mi = 0; mi < 2; ++mi)
      #pragma unroll
      for (int ni = 0; ni < 2; ++ni)
        #pragma unroll
        for (int r = 0; r < 4; ++r)
          pbuf[(mi * 16 + quad * 4 + r) * 40 + ni * 16 + l15] = f2b(p[mi][ni][r]);
    short8 pf[2];
    #pragma unroll
    for (int mi = 0; mi < 2; ++mi)
      pf[mi] = *(const short8*)(pbuf + (mi * 16 + l15) * 40 + quad * 8);

    #pragma unroll
    for (int nj = 0; nj < 8; ++nj) {
      short8 vf = *(const short8*)(Vb + (size_t)(nj * 16 + l15) * SEQ + k0 + quad * 8);
      #pragma unroll
      for (int mi = 0; mi < 2; ++mi)
        o[mi][nj] = __builtin_amdgcn_mfma_f32_16x16x32_bf16(pf[mi], vf, o[mi][nj], 0, 0, 0);
    }
  }

  float rl[2][4];
  #pragma unroll
  for (int mi = 0; mi < 2; ++mi)
    #pragma unroll
    for (int r = 0; r < 4; ++r) rl[mi][r] = 1.0f / lst[mi][r];
  #pragma unroll
  for (int mi = 0; mi < 2; ++mi)
    #pragma unroll
    for (int nj = 0; nj < 8; ++nj)
      #pragma unroll
      for (int r = 0; r < 4; ++r) {
        int m = q0 + mi * 16 + quad * 4 + r;
        Aout[((size_t)(b * SEQ + m)) * D_MODEL + h * HD + nj * 16 + l15] =
            f2b(o[mi][nj][r] * rl[mi][r]);
      }
}

extern "C" void kernel_launch(void* const* d_in, const int* in_sizes, int n_in,
                              void* d_out, int out_size, void* d_ws, size_t ws_size,
                              hipStream_t stream)
{
  const float* x  = (const float*)d_in[0];
  const float* Wq = (const float*)d_in[1];
  const float* Wk = (const float*)d_in[2];
  const float* Wv = (const float*)d_in[3];
  const float* Wo = (const float*)d_in[4];
  float* out = (float*)d_out;

  unsigned short* xb  = (unsigned short*)d_ws;        // 8M
  unsigned short* wqb = xb  + 8388608;                // 4M each
  unsigned short* wkb = wqb + 4194304;
  unsigned short* wvb = wkb + 4194304;
  unsigned short* wob = wvb + 4194304;
  unsigned short* qh  = wob + 4194304;                // 8M each
  unsigned short* kh  = qh  + 8388608;
  unsigned short* vt  = kh  + 8388608;
  unsigned short* ao  = vt  + 8388608;                // total 112 MB

  cast_all<<<24576, 256, 0, stream>>>(x, Wq, Wk, Wv, Wo, xb);
  gemm_qkv<<<dim3(16, 32, 3), 256, 0, stream>>>(xb, wqb, wkb, wvb, qh, kh, vt);
  rope_k<<<dim3(16384, 2), 256, 0, stream>>>(qh, kh);
  attn_k<<<dim3(16, 32), 256, 0, stream>>>(qh, kh, vt, ao);
  gemm_out<<<dim3(16, 32), 256, 0, stream>>>(ao, wob, out);
}

// Round 3
// 430.242 us; speedup vs baseline: 1.4230x; 1.4230x over previous
//
#include <hip/hip_runtime.h>
#include <stdint.h>

#define D_MODEL 2048
#define SEQ     2048
#define BATCH   2
#define NHEAD   16
#define HD      128
#define MROWS   (BATCH*SEQ)   // 4096

typedef short short8 __attribute__((ext_vector_type(8)));
typedef float f32x4  __attribute__((ext_vector_type(4)));

__device__ __forceinline__ unsigned short f2b(float f) {
  unsigned int u = __float_as_uint(f);
  u += 0x7fffu + ((u >> 16) & 1u);          // RNE
  return (unsigned short)(u >> 16);
}
__device__ __forceinline__ float b2f(unsigned short s) {
  return __uint_as_float(((unsigned int)s) << 16);
}
__device__ __forceinline__ void gll16(const void* g, void* l) {
  __builtin_amdgcn_global_load_lds((const __attribute__((address_space(1))) void*)g,
                                   (__attribute__((address_space(3))) void*)l, 16, 0, 0);
}

// ---------------- cast fp32 -> bf16 (x | Wq | Wk | Wv | Wo contiguous) ----------------
__global__ __launch_bounds__(256) void cast_all(
    const float* __restrict__ x,  const float* __restrict__ Wq,
    const float* __restrict__ Wk, const float* __restrict__ Wv,
    const float* __restrict__ Wo, unsigned short* __restrict__ dst)
{
  size_t e = ((size_t)blockIdx.x * 256 + threadIdx.x) * 4;
  const size_t XN = (size_t)MROWS * D_MODEL;   // 2^23
  const size_t WN = (size_t)D_MODEL * D_MODEL; // 2^22
  const float* src; size_t off;
  if (e < XN) { src = x; off = e; }
  else {
    size_t e2 = e - XN;
    int w = (int)(e2 >> 22);
    off = e2 & (WN - 1);
    src = (w == 0) ? Wq : (w == 1) ? Wk : (w == 2) ? Wv : Wo;
  }
  float4 v = *(const float4*)(src + off);
  ushort4 o;
  o.x = f2b(v.x); o.y = f2b(v.y); o.z = f2b(v.z); o.w = f2b(v.w);
  *(ushort4*)(dst + e) = o;
}

// ---------------- m97-style 128x128 bf16 GEMM core: C = A @ B^T ----------------
__device__ __forceinline__ void gemm_core(
    const unsigned short* __restrict__ A, const unsigned short* __restrict__ Bw,
    unsigned short* As, unsigned short* Bs, int m0, int n0, int tid,
    f32x4 (&acc)[4][4])
{
  const int K = D_MODEL;
  const int wave = tid >> 6, lane = tid & 63, l15 = lane & 15, quad = lane >> 4;
  const int wr = wave >> 1, wc = wave & 1;

  for (int kt = 0; kt < K; kt += 32) {
    #pragma unroll
    for (int c = 0; c < 2; ++c) {
      int chunk = c * 256 + tid;
      const unsigned short* ga = A  + (size_t)(m0 + (chunk >> 2)) * K + kt + (chunk & 3) * 8;
      const unsigned short* gb = Bw + (size_t)(n0 + (chunk >> 2)) * K + kt + (chunk & 3) * 8;
      gll16(ga, As + (size_t)(c * 256 + wave * 64) * 8);
      gll16(gb, Bs + (size_t)(c * 256 + wave * 64) * 8);
    }
    __syncthreads();
    short8 af[4], bfr[4];
    #pragma unroll
    for (int mi = 0; mi < 4; ++mi)
      af[mi] = *(const short8*)(As + (wr * 64 + mi * 16 + l15) * 32 + quad * 8);
    #pragma unroll
    for (int ni = 0; ni < 4; ++ni)
      bfr[ni] = *(const short8*)(Bs + (wc * 64 + ni * 16 + l15) * 32 + quad * 8);
    #pragma unroll
    for (int mi = 0; mi < 4; ++mi)
      #pragma unroll
      for (int ni = 0; ni < 4; ++ni)
        acc[mi][ni] = __builtin_amdgcn_mfma_f32_16x16x32_bf16(af[mi], bfr[ni], acc[mi][ni], 0, 0, 0);
    __syncthreads();
  }
}

__global__ __launch_bounds__(256) void gemm_qkv(
    const unsigned short* __restrict__ Axb,
    const unsigned short* __restrict__ Wq, const unsigned short* __restrict__ Wk,
    const unsigned short* __restrict__ Wv,
    unsigned short* __restrict__ Qh, unsigned short* __restrict__ Kh,
    unsigned short* __restrict__ Vt)
{
  __shared__ unsigned short As[128 * 32], Bs[128 * 32];
  const int z = blockIdx.z;
  const unsigned short* Bw = (z == 0) ? Wq : (z == 1) ? Wk : Wv;
  const int m0 = blockIdx.y * 128, n0 = blockIdx.x * 128;
  f32x4 acc[4][4];
  #pragma unroll
  for (int i = 0; i < 4; ++i)
    #pragma unroll
    for (int j = 0; j < 4; ++j) acc[i][j] = (f32x4){0.f, 0.f, 0.f, 0.f};
  gemm_core(Axb, Bw, As, Bs, m0, n0, threadIdx.x, acc);

  const int tid = threadIdx.x, wave = tid >> 6, lane = tid & 63;
  const int l15 = lane & 15, quad = lane >> 4, wr = wave >> 1, wc = wave & 1;
  if (z < 2) {
    unsigned short* dst = z ? Kh : Qh;
    #pragma unroll
    for (int mi = 0; mi < 4; ++mi)
      #pragma unroll
      for (int ni = 0; ni < 4; ++ni) {
        int row0 = m0 + wr * 64 + mi * 16 + quad * 4;
        int col  = n0 + wc * 64 + ni * 16 + l15;
        int h = col >> 7, d = col & (HD - 1);
        #pragma unroll
        for (int r = 0; r < 4; ++r) {
          int m = row0 + r; int bb = m >> 11; int s = m & (SEQ - 1);
          dst[((size_t)(bb * NHEAD + h) * SEQ + s) * HD + d] = f2b(acc[mi][ni][r]);
        }
      }
  } else {
    #pragma unroll
    for (int mi = 0; mi < 4; ++mi)
      #pragma unroll
      for (int ni = 0; ni < 4; ++ni) {
        int row0 = m0 + wr * 64 + mi * 16 + quad * 4;
        int col  = n0 + wc * 64 + ni * 16 + l15;
        int h = col >> 7, d = col & (HD - 1);
        int bb = row0 >> 11; int s = row0 & (SEQ - 1);
        ushort4 pk;
        pk.x = f2b(acc[mi][ni][0]); pk.y = f2b(acc[mi][ni][1]);
        pk.z = f2b(acc[mi][ni][2]); pk.w = f2b(acc[mi][ni][3]);
        *(ushort4*)(Vt + ((size_t)(bb * NHEAD + h) * HD + d) * SEQ + s) = pk;
      }
  }
}

__global__ __launch_bounds__(256) void gemm_out(
    const unsigned short* __restrict__ A, const unsigned short* __restrict__ Wo,
    float* __restrict__ C)
{
  __shared__ unsigned short As[128 * 32], Bs[128 * 32];
  const int m0 = blockIdx.y * 128, n0 = blockIdx.x * 128;
  f32x4 acc[4][4];
  #pragma unroll
  for (int i = 0; i < 4; ++i)
    #pragma unroll
    for (int j = 0; j < 4; ++j) acc[i][j] = (f32x4){0.f, 0.f, 0.f, 0.f};
  gemm_core(A, Wo, As, Bs, m0, n0, threadIdx.x, acc);

  const int tid = threadIdx.x, wave = tid >> 6, lane = tid & 63;
  const int l15 = lane & 15, quad = lane >> 4, wr = wave >> 1, wc = wave & 1;
  #pragma unroll
  for (int mi = 0; mi < 4; ++mi)
    #pragma unroll
    for (int ni = 0; ni < 4; ++ni) {
      int row0 = m0 + wr * 64 + mi * 16 + quad * 4;
      int col  = n0 + wc * 64 + ni * 16 + l15;
      #pragma unroll
      for (int r = 0; r < 4; ++r)
        C[(size_t)(row0 + r) * D_MODEL + col] = acc[mi][ni][r];
    }
}

// ---------------- RoPE in place on [b,h,s,d] bf16 ----------------
__global__ __launch_bounds__(256) void rope_k(unsigned short* __restrict__ Qh,
                                              unsigned short* __restrict__ Kh)
{
  unsigned short* P = blockIdx.y ? Kh : Qh;
  int rid = blockIdx.x * 4 + (threadIdx.x >> 6);
  int i = threadIdx.x & 63;
  int s = rid & (SEQ - 1);
  size_t base = (size_t)rid * HD + 2 * i;
  float inv = exp2f(-(float)i * (13.287712379549449f / 64.0f));
  float ang = (float)s * inv;
  float sn, cs; sincosf(ang, &sn, &cs);
  unsigned int pk = *(const unsigned int*)(P + base);
  float x1 = b2f((unsigned short)(pk & 0xffffu));
  float x2 = b2f((unsigned short)(pk >> 16));
  unsigned short o0 = f2b(x1 * cs - x2 * sn);
  unsigned short o1 = f2b(x1 * sn + x2 * cs);
  *(unsigned int*)(P + base) = (unsigned int)o0 | ((unsigned int)o1 << 16);
}

// ---------------- flash attention v3 ----------------
// 64 q-rows/block (4 waves x 16 rows), k-tile 64 staged in LDS (xor-swizzled),
// S^T via mfma(kf,qf): lane's scores all belong to q-row l15.
// O^T via mfma(vf,pf): lane's accumulators ALL belong to q-row l15, so per-lane
// online-softmax state (ms, ls, al) applies directly -- no cross-row realignment.
// Paired q-tiles (t, 31-t) give uniform 33 rounds/block.
__global__ __launch_bounds__(256) void attn_k(
    const unsigned short* __restrict__ Qh, const unsigned short* __restrict__ Kh,
    const unsigned short* __restrict__ Vt, unsigned short* __restrict__ Aout)
{
  __shared__ unsigned short Ks[64 * 128];    // 16 KB, chunk' = chunk ^ (row&15)
  __shared__ unsigned short Vs[128 * 64];    // 16 KB, chunk' = chunk ^ (row&7)
  __shared__ unsigned short sPb[4][16 * 72]; // 9 KB, per-wave P, stride 72
  const int tid = threadIdx.x;
  const int wave = tid >> 6, lane = tid & 63, l15 = lane & 15, quad = lane >> 4;
  const int bh = blockIdx.y;
  const int b = bh >> 4, h = bh & 15;
  const unsigned short* Qb = Qh + (size_t)bh * SEQ * HD;
  const unsigned short* Kb = Kh + (size_t)bh * SEQ * HD;
  const unsigned short* Vb = Vt + (size_t)bh * HD * SEQ;
  unsigned short* pw = &sPb[wave][0];
  const float scl = 0.08838834764831845f * 1.4426950408889634f; // 1/sqrt(128)*log2(e)

  #pragma unroll
  for (int half = 0; half < 2; ++half) {
    const int tile = half ? (31 - blockIdx.x) : blockIdx.x;
    const int q0b = tile * 64;
    const int q0w = q0b + wave * 16;
    const int q = q0w + l15;          // this lane's q-row

    short8 qf[4];
    #pragma unroll
    for (int c = 0; c < 4; ++c)
      qf[c] = *(const short8*)(Qb + (size_t)(q0w + l15) * HD + c * 32 + quad * 8);

    f32x4 o[8];                       // O^T: o[dj][r] = O[q][dj*16 + quad*4 + r]
    #pragma unroll
    for (int dj = 0; dj < 8; ++dj) o[dj] = (f32x4){0.f, 0.f, 0.f, 0.f};
    float ms = -1e30f, ls = 0.f;

    const int trips = tile + 1;
    for (int it = 0; it < trips; ++it) {
      const int k0 = it * 64;
      __syncthreads();   // previous round's LDS reads complete
      #pragma unroll
      for (int c = 0; c < 4; ++c) {       // stage K tile: 64 x 128
        int slot = c * 256 + tid;
        int kr = slot >> 4, pch = slot & 15;
        gll16(Kb + (size_t)(k0 + kr) * HD + ((pch ^ (kr & 15)) * 8), Ks + slot * 8);
      }
      #pragma unroll
      for (int c = 0; c < 4; ++c) {       // stage V^T tile: 128 x 64
        int slot = c * 256 + tid;
        int vr = slot >> 3, pch = slot & 7;
        gll16(Vb + (size_t)vr * SEQ + k0 + ((pch ^ (vr & 7)) * 8), Vs + slot * 8);
      }
      __syncthreads();   // staging visible

      // S^T = K_tile @ Q^T : row = k (quad*4+r), col = q (l15)
      f32x4 st[4];
      #pragma unroll
      for (int ni = 0; ni < 4; ++ni) st[ni] = (f32x4){0.f, 0.f, 0.f, 0.f};
      #pragma unroll
      for (int ni = 0; ni < 4; ++ni) {
        const int rowb = (ni * 16 + l15) * 128;
        #pragma unroll
        for (int c = 0; c < 4; ++c) {
          short8 kf = *(const short8*)(Ks + rowb + (((c * 4 + quad) ^ l15) * 8));
          st[ni] = __builtin_amdgcn_mfma_f32_16x16x32_bf16(kf, qf[c], st[ni], 0, 0, 0);
        }
      }

      // causal mask (only near diagonal)
      if (k0 + 63 > q0w) {
        #pragma unroll
        for (int ni = 0; ni < 4; ++ni)
          #pragma unroll
          for (int r = 0; r < 4; ++r) {
            int k = k0 + ni * 16 + quad * 4 + r;
            if (k > q) st[ni][r] = -1e30f;
          }
      }

      // online softmax: per-lane (q-row l15) + 2 shuffles across quad partners
      float lm = -1e30f;
      #pragma unroll
      for (int ni = 0; ni < 4; ++ni)
        #pragma unroll
        for (int r = 0; r < 4; ++r) lm = fmaxf(lm, st[ni][r]);
      lm = fmaxf(lm, __shfl_xor(lm, 16, 64));
      lm = fmaxf(lm, __shfl_xor(lm, 32, 64));
      float mn = fmaxf(ms, lm);
      float al = exp2f((ms - mn) * scl);
      ms = mn;
      float nm = mn * scl;
      float rs = 0.f;
      #pragma unroll
      for (int ni = 0; ni < 4; ++ni)
        #pragma unroll
        for (int r = 0; r < 4; ++r) {
          float p = exp2f(fmaf(st[ni][r], scl, -nm));
          st[ni][r] = p;
          rs += p;
        }
      rs += __shfl_xor(rs, 16, 64);
      rs += __shfl_xor(rs, 32, 64);
      ls = ls * al + rs;
      #pragma unroll
      for (int dj = 0; dj < 8; ++dj) o[dj] *= al;   // O^T rows all q=l15: al aligned

      // P^T (st) -> wave-private LDS as P[q=l15][k], read back as B-operand
      #pragma unroll
      for (int ni = 0; ni < 4; ++ni) {
        ushort4 pk;
        pk.x = f2b(st[ni][0]); pk.y = f2b(st[ni][1]);
        pk.z = f2b(st[ni][2]); pk.w = f2b(st[ni][3]);
        *(ushort4*)(pw + l15 * 72 + ni * 16 + quad * 4) = pk;
      }
      short8 pf0 = *(const short8*)(pw + l15 * 72 + quad * 8);
      short8 pf1 = *(const short8*)(pw + l15 * 72 + 32 + quad * 8);

      // O^T += V^T_tile @ P^T : mfma(A=vf, B=pf) -> D[m=d-offset][n=q]
      #pragma unroll
      for (int dj = 0; dj < 8; ++dj) {
        const int vrow = (dj * 16 + l15) * 64;
        short8 v0 = *(const short8*)(Vs + vrow + (((quad) ^ (l15 & 7)) * 8));
        short8 v1 = *(const short8*)(Vs + vrow + (((4 + quad) ^ (l15 & 7)) * 8));
        o[dj] = __builtin_amdgcn_mfma_f32_16x16x32_bf16(v0, pf0, o[dj], 0, 0, 0);
        o[dj] = __builtin_amdgcn_mfma_f32_16x16x32_bf16(v1, pf1, o[dj], 0, 0, 0);
      }
    }

    // epilogue: o[dj][r] = O[q = q0w+l15][d = dj*16 + quad*4 + r] (unnormalized)
    float rl = 1.0f / ls;
    #pragma unroll
    for (int dj = 0; dj < 8; ++dj) {
      ushort4 pk;
      pk.x = f2b(o[dj][0] * rl); pk.y = f2b(o[dj][1] * rl);
      pk.z = f2b(o[dj][2] * rl); pk.w = f2b(o[dj][3] * rl);
      *(ushort4*)(Aout + ((size_t)(b * SEQ + q)) * D_MODEL + h * HD + dj * 16 + quad * 4) = pk;
    }
  }
}

extern "C" void kernel_launch(void* const* d_in, const int* in_sizes, int n_in,
                              void* d_out, int out_size, void* d_ws, size_t ws_size,
                              hipStream_t stream)
{
  const float* x  = (const float*)d_in[0];
  const float* Wq = (const float*)d_in[1];
  const float* Wk = (const float*)d_in[2];
  const float* Wv = (const float*)d_in[3];
  const float* Wo = (const float*)d_in[4];
  float* out = (float*)d_out;

  unsigned short* xb  = (unsigned short*)d_ws;        // 8M
  unsigned short* wqb = xb  + 8388608;                // 4M each
  unsigned short* wkb = wqb + 4194304;
  unsigned short* wvb = wkb + 4194304;
  unsigned short* wob = wvb + 4194304;
  unsigned short* qh  = wob + 4194304;                // 8M each
  unsigned short* kh  = qh  + 8388608;
  unsigned short* vt  = kh  + 8388608;
  unsigned short* ao  = vt  + 8388608;                // total 112 MB

  cast_all<<<24576, 256, 0, stream>>>(x, Wq, Wk, Wv, Wo, xb);
  gemm_qkv<<<dim3(16, 32, 3), 256, 0, stream>>>(xb, wqb, wkb, wvb, qh, kh, vt);
  rope_k<<<dim3(16384, 2), 256, 0, stream>>>(qh, kh);
  attn_k<<<dim3(16, 32), 256, 0, stream>>>(qh, kh, vt, ao);
  gemm_out<<<dim3(16, 32), 256, 0, stream>>>(ao, wob, out);
}